// Round 5
// baseline (113.587 us; speedup 1.0000x reference)
//
#include <hip/hip_runtime.h>

// GenomeNet: B=4096, N_IN=W=N_OUT=1024, L=8 hidden, D=16 fan-in.
// R11: R10 structure (TB=16, lane-pair-split 32B rows, cross-pass load
// pipelining, weight prefetch) + v_perm/v_dot2_f32_f16 inner loop.
//   R10 post-mortem: 3 scheduling experiments all neutral at ~48.5us.
//   Limiter model: LDS pipe 9.4k cyc/CU/layer (73% util) + ~3.5k of
//   non-overlapped VALU (compiler emits cvt_f32_f16+fma per element =
//   256 instr/pass). Fix: halve MAC VALU via v_perm_b32 packing
//   {edge_e[j], edge_e1[j]} into half2 + v_dot2_f32_f16 (fp16 products
//   exact in f32, f32 accumulate). Weights converted to fp16 pairs once
//   per pass (RTN, rel err 2^-11 -- negligible vs 2^-7 absmax scale).

#define TB       16
#define W_NODES  1024
#define LAYERS   8
#define ROW_H    16                    // halfs per node row (32 B)
#define BUF_H    (W_NODES * ROW_H)     // 16384 halfs = 32 KB

typedef _Float16 h8      __attribute__((ext_vector_type(8)));
typedef _Float16 half2_t __attribute__((ext_vector_type(2)));
typedef unsigned int u32x4 __attribute__((ext_vector_type(4)));

#define SEL_LO 0x05040100u   // D = {S1.b0,S1.b1, S0.b0,S0.b1} = {ga.h0, gb.h0}
#define SEL_HI 0x07060302u   // D = {S1.b2,S1.b3, S0.b2,S0.b3} = {ga.h1, gb.h1}

__device__ __forceinline__ float fast_tanh(float x) {
    // tanh(x) = 1 - 2/(e^{2x}+1)
    float a = __builtin_amdgcn_exp2f(x * 2.8853900817779268f);
    return 1.0f - 2.0f * __builtin_amdgcn_rcpf(a + 1.0f);
}

// Per-node edge data: 16 src indices + 16 weights, packed in regs.
struct SW { int4 s[4]; float4 w[4]; };

__device__ __forceinline__ void load_sw(const int4* __restrict__ sp,
                                        const float4* __restrict__ wp,
                                        SW& d) {
    #pragma unroll
    for (int q = 0; q < 4; ++q) { d.s[q] = sp[q]; d.w[q] = wp[q]; }
}

// Unpack indices + convert weights to packed fp16 pairs (RTN casts).
__device__ __forceinline__ void unpack_sw(const SW& d,
                                          int* __restrict__ si,
                                          half2_t* __restrict__ wp) {
    #pragma unroll
    for (int q = 0; q < 4; ++q) {
        si[4*q+0] = d.s[q].x; si[4*q+1] = d.s[q].y;
        si[4*q+2] = d.s[q].z; si[4*q+3] = d.s[q].w;
        half2_t w01, w23;
        w01[0] = (_Float16)d.w[q].x; w01[1] = (_Float16)d.w[q].y;
        w23[0] = (_Float16)d.w[q].z; w23[1] = (_Float16)d.w[q].w;
        wp[2*q+0] = w01;
        wp[2*q+1] = w23;
    }
}

// acc[j] += ga[j]*w01[0] + gb[j]*w01[1] for j=0..7.
// Per dword d: ga dword d = batches {2d lo, 2d+1 hi}; perm builds
// {ga[j], gb[j]} half2, fdot2 does both fp16 products + f32 accumulate.
#define FMA_PAIR(acc, ga, gb, w01)                                          \
    do {                                                                    \
        const u32x4 _a = __builtin_bit_cast(u32x4, (ga));                   \
        const u32x4 _b = __builtin_bit_cast(u32x4, (gb));                   \
        const half2_t _w = (w01);                                           \
        _Pragma("unroll")                                                   \
        for (int d = 0; d < 4; ++d) {                                       \
            unsigned _plo = __builtin_amdgcn_perm(_b[d], _a[d], SEL_LO);    \
            unsigned _phi = __builtin_amdgcn_perm(_b[d], _a[d], SEL_HI);    \
            acc[2*d+0] = __builtin_amdgcn_fdot2(                            \
                __builtin_bit_cast(half2_t, _plo), _w, acc[2*d+0], false);  \
            acc[2*d+1] = __builtin_amdgcn_fdot2(                            \
                __builtin_bit_cast(half2_t, _phi), _w, acc[2*d+1], false);  \
        }                                                                   \
    } while (0)

__global__ __launch_bounds__(1024, 4) void genome_net(
    const float* __restrict__ x,
    const int*   __restrict__ src_hidden,
    const float* __restrict__ w_hidden,
    const int*   __restrict__ src_out,
    const float* __restrict__ w_out,
    float*       __restrict__ out)
{
    extern __shared__ _Float16 lds[];
    _Float16* bufA = lds;              // [1024 nodes][16 batch] fp16, 32 KB
    _Float16* bufB = lds + BUF_H;

    const int t   = threadIdx.x;
    const int pr  = t >> 1;            // pair index 0..511
    const int hf  = t & 1;             // which 16 B half of the row
    const int hfo = hf << 3;           // half offset in halfs
    const int b0  = blockIdx.x * TB;
    const int bb  = b0 + hfo;          // this thread's 8-batch base

    const int n0 = pr;                 // pass-0 node
    const int n1 = 512 + pr;           // pass-1 node

    const int4*   shp = (const int4*)src_hidden;
    const float4* whp = (const float4*)w_hidden;
    const int4*   sop = (const int4*)src_out;
    const float4* wop = (const float4*)w_out;

    // ---- Prefetch layer-0 weights (in flight under x-staging + barrier).
    SW A, B;
    load_sw(shp + (n0 << 2), whp + (n0 << 2), A);
    load_sw(shp + (n1 << 2), whp + (n1 << 2), B);

    // ---- Stage x: fp32 -> fp16 half-rows, 2 node passes. Coalesced.
    #pragma unroll
    for (int p = 0; p < 2; ++p) {
        const int n = (p << 9) + pr;
        h8 hv;
        #pragma unroll
        for (int j = 0; j < 8; ++j)
            hv[j] = (_Float16)x[(size_t)(bb + j) * W_NODES + n];
        *(h8*)(bufA + n * ROW_H + hfo) = hv;   // 8 lanes/quad-group: clean
    }
    __syncthreads();

    _Float16* rd = bufA;
    _Float16* wr = bufB;

#define LDV(S, i) (*(const h8*)(rd + ((S[i] << 4) + hfo)))

    #pragma unroll 1
    for (int l = 0; l < LAYERS; ++l) {
        int     si0[16], si1[16];
        half2_t wp0[8],  wp1[8];
        unpack_sw(A, si0, wp0);
        unpack_sw(B, si1, wp1);

        const bool last = (l == LAYERS - 1);
        const int  rn0 = ((l + 1) << 10) + n0;
        const int  rn1 = ((l + 1) << 10) + n1;
        const int4*   spA = last ? sop + (n0 << 2) : shp + (rn0 << 2);
        const float4* wpA = last ? wop + (n0 << 2) : whp + (rn0 << 2);
        const int4*   spB = last ? sop + (n1 << 2) : shp + (rn1 << 2);
        const float4* wpB = last ? wop + (n1 << 2) : whp + (rn1 << 2);

        float acc0[8], acc1[8];
        #pragma unroll
        for (int j = 0; j < 8; ++j) acc0[j] = 0.0f;

        // ---- pass 0 gather: rolling 8-deep, consumed in edge pairs.
        h8 g0 = LDV(si0, 0);  h8 g1 = LDV(si0, 1);
        h8 g2 = LDV(si0, 2);  h8 g3 = LDV(si0, 3);
        h8 g4 = LDV(si0, 4);  h8 g5 = LDV(si0, 5);
        h8 g6 = LDV(si0, 6);  h8 g7 = LDV(si0, 7);

        FMA_PAIR(acc0, g0, g1, wp0[0]);
        g0 = LDV(si0, 8);        g1 = LDV(si0, 9);
        FMA_PAIR(acc0, g2, g3, wp0[1]);
        g2 = LDV(si0, 10);       g3 = LDV(si0, 11);
        FMA_PAIR(acc0, g4, g5, wp0[2]);
        g4 = LDV(si0, 12);       g5 = LDV(si0, 13);
        FMA_PAIR(acc0, g6, g7, wp0[3]);
        g6 = LDV(si0, 14);       g7 = LDV(si0, 15);

        // ---- pass-0 tail; issue pass-1's first 8 loads to keep the LDS
        // pipe fed through the tanh-0 tail.
        h8 h0 = LDV(si1, 0);     h8 h1 = LDV(si1, 1);
        FMA_PAIR(acc0, g0, g1, wp0[4]);
        h8 h2 = LDV(si1, 2);     h8 h3 = LDV(si1, 3);
        FMA_PAIR(acc0, g2, g3, wp0[5]);
        h8 h4 = LDV(si1, 4);     h8 h5 = LDV(si1, 5);
        FMA_PAIR(acc0, g4, g5, wp0[6]);
        h8 h6 = LDV(si1, 6);     h8 h7 = LDV(si1, 7);
        FMA_PAIR(acc0, g6, g7, wp0[7]);

        // tanh + write pass 0 (pass-1 loads in flight).
        {
            h8 hv;
            #pragma unroll
            for (int j = 0; j < 8; ++j) hv[j] = (_Float16)fast_tanh(acc0[j]);
            *(h8*)(wr + n0 * ROW_H + hfo) = hv;
        }

        // next-layer pass-0 weights: one full compute-pass ahead of use.
        load_sw(spA, wpA, A);

        #pragma unroll
        for (int j = 0; j < 8; ++j) acc1[j] = 0.0f;

        // ---- pass 1: first 8 already in flight, keep rolling.
        FMA_PAIR(acc1, h0, h1, wp1[0]);
        h0 = LDV(si1, 8);        h1 = LDV(si1, 9);
        FMA_PAIR(acc1, h2, h3, wp1[1]);
        h2 = LDV(si1, 10);       h3 = LDV(si1, 11);
        FMA_PAIR(acc1, h4, h5, wp1[2]);
        h4 = LDV(si1, 12);       h5 = LDV(si1, 13);
        FMA_PAIR(acc1, h6, h7, wp1[3]);
        h6 = LDV(si1, 14);       h7 = LDV(si1, 15);

        FMA_PAIR(acc1, h0, h1, wp1[4]);
        FMA_PAIR(acc1, h2, h3, wp1[5]);
        FMA_PAIR(acc1, h4, h5, wp1[6]);
        FMA_PAIR(acc1, h6, h7, wp1[7]);

        // next-layer pass-1 weights (needed only after next pass-0).
        load_sw(spB, wpB, B);

        // tanh + write pass 1.
        {
            h8 hv;
            #pragma unroll
            for (int j = 0; j < 8; ++j) hv[j] = (_Float16)fast_tanh(acc1[j]);
            *(h8*)(wr + n1 * ROW_H + hfo) = hv;
        }

        __syncthreads();
        _Float16* tmp = rd; rd = wr; wr = tmp;
    }

    // ---- Output layer: identity activation, fused passes, fp32 stores.
    {
        int     si0[16], si1[16];
        half2_t wp0[8],  wp1[8];
        unpack_sw(A, si0, wp0);
        unpack_sw(B, si1, wp1);

        float acc0[8], acc1[8];
        #pragma unroll
        for (int j = 0; j < 8; ++j) acc0[j] = 0.0f;

        h8 g0 = LDV(si0, 0);  h8 g1 = LDV(si0, 1);
        h8 g2 = LDV(si0, 2);  h8 g3 = LDV(si0, 3);
        h8 g4 = LDV(si0, 4);  h8 g5 = LDV(si0, 5);
        h8 g6 = LDV(si0, 6);  h8 g7 = LDV(si0, 7);

        FMA_PAIR(acc0, g0, g1, wp0[0]);
        g0 = LDV(si0, 8);        g1 = LDV(si0, 9);
        FMA_PAIR(acc0, g2, g3, wp0[1]);
        g2 = LDV(si0, 10);       g3 = LDV(si0, 11);
        FMA_PAIR(acc0, g4, g5, wp0[2]);
        g4 = LDV(si0, 12);       g5 = LDV(si0, 13);
        FMA_PAIR(acc0, g6, g7, wp0[3]);
        g6 = LDV(si0, 14);       g7 = LDV(si0, 15);

        h8 h0 = LDV(si1, 0);     h8 h1 = LDV(si1, 1);
        FMA_PAIR(acc0, g0, g1, wp0[4]);
        h8 h2 = LDV(si1, 2);     h8 h3 = LDV(si1, 3);
        FMA_PAIR(acc0, g2, g3, wp0[5]);
        h8 h4 = LDV(si1, 4);     h8 h5 = LDV(si1, 5);
        FMA_PAIR(acc0, g4, g5, wp0[6]);
        h8 h6 = LDV(si1, 6);     h8 h7 = LDV(si1, 7);
        FMA_PAIR(acc0, g6, g7, wp0[7]);

        // stores for pass 0 (pass-1 loads in flight); coalesced per j.
        #pragma unroll
        for (int j = 0; j < 8; ++j)
            out[(size_t)(bb + j) * W_NODES + n0] = acc0[j];

        #pragma unroll
        for (int j = 0; j < 8; ++j) acc1[j] = 0.0f;

        FMA_PAIR(acc1, h0, h1, wp1[0]);
        h0 = LDV(si1, 8);        h1 = LDV(si1, 9);
        FMA_PAIR(acc1, h2, h3, wp1[1]);
        h2 = LDV(si1, 10);       h3 = LDV(si1, 11);
        FMA_PAIR(acc1, h4, h5, wp1[2]);
        h4 = LDV(si1, 12);       h5 = LDV(si1, 13);
        FMA_PAIR(acc1, h6, h7, wp1[3]);
        h6 = LDV(si1, 14);       h7 = LDV(si1, 15);

        FMA_PAIR(acc1, h0, h1, wp1[4]);
        FMA_PAIR(acc1, h2, h3, wp1[5]);
        FMA_PAIR(acc1, h4, h5, wp1[6]);
        FMA_PAIR(acc1, h6, h7, wp1[7]);

        #pragma unroll
        for (int j = 0; j < 8; ++j)
            out[(size_t)(bb + j) * W_NODES + n1] = acc1[j];
    }

#undef LDV
}

extern "C" void kernel_launch(void* const* d_in, const int* in_sizes, int n_in,
                              void* d_out, int out_size, void* d_ws, size_t ws_size,
                              hipStream_t stream) {
    const float* x  = (const float*)d_in[0];
    const int*   sh = (const int*)  d_in[1];
    const float* wh = (const float*)d_in[2];
    const int*   so = (const int*)  d_in[3];
    const float* wo = (const float*)d_in[4];
    float* out = (float*)d_out;

    const int shmem = 2 * BUF_H * (int)sizeof(_Float16);   // 65536 B
    hipFuncSetAttribute(reinterpret_cast<const void*>(genome_net),
                        hipFuncAttributeMaxDynamicSharedMemorySize, shmem);

    genome_net<<<dim3(4096 / TB), dim3(1024), shmem, stream>>>(
        x, sh, wh, so, wo, out);
}